// Round 15
// baseline (208.957 us; speedup 1.0000x reference)
//
#include <hip/hip_runtime.h>

#define BS 16
#define NH 16
#define LQ 4096
#define DH 32

constexpr size_t OUT_ELEMS = (size_t)BS * NH * LQ * DH;   // 33,554,432
constexpr int HDE = NH * DH * DH;           // 16384

// global -> LDS direct copy, 16 B per lane. dst is the WAVE-UNIFORM base;
// HW writes dst + lane*16. src is per-lane.
__device__ __forceinline__ void async_cp16(float* dst, const float* src) {
    __builtin_amdgcn_global_load_lds(
        (const __attribute__((address_space(1))) void*)src,
        (__attribute__((address_space(3))) void*)dst, 16, 0, 0);
}

__device__ __forceinline__ void fma4(float4& a, float s, const float4& v) {
    a.x = fmaf(s, v.x, a.x);
    a.y = fmaf(s, v.y, a.y);
    a.z = fmaf(s, v.z, a.z);
    a.w = fmaf(s, v.w, a.w);
}

// ---------------- Kernel A: partial K@V ----------------
// R12 codegen (VGPR 68, known-good 97us) + ONE change: __launch_bounds__(256,5).
// Calibration: qw (identical per-thread profile) runs 26us; kv's 4x gap is
// occupancy (28%, 2.25 blocks/CU) x per-wave stalls from compiler-sunk V
// loads. 5 blocks/CU = 20 waves = 62% occupancy; VGPR cap 102 >> achieved 68
// so no R13-style spill. pin4 removed (R14: no-op, pins sink with loads).
template<int NCH>
__global__ __launch_bounds__(256, 5) void kv_partial(const float* __restrict__ k,
                                                     const float* __restrict__ v,
                                                     float* __restrict__ part) {
    __shared__ float lds[4608];             // K[32][128] swz (4096) / reduce 4x1152
    const int tid = threadIdx.x;
    const int w   = tid >> 6;
    const int l   = tid & 63;
    const int nsplit = 32 / NCH;
    const int p  = blockIdx.x % nsplit;
    const int bh = blockIdx.x / nsplit;

    const int tw = tid & 31;
    const int sp = tid >> 5;                // 0..7
    const int dg = tw >> 3;                 // 0..3
    const int eg = tw & 7;                  // 0..7
    const int d0 = dg << 3;
    const int e0 = eg << 2;

    const float* kb = k + (size_t)bh * DH * LQ;
    const float* vb = v + (size_t)bh * LQ * DH;

    // K gll source constants: instr j covers rows {2j,2j+1}; lane l -> row
    // d = 2j + (l>>5), stored chunk cs = l&31 holds source chunk cs ^ ((j>>2)&3)
    size_t ksrc[4];
#pragma unroll
    for (int jj = 0; jj < 4; ++jj) {
        const int j = (w << 2) | jj;
        const int d = (j << 1) + (l >> 5);
        const int csrc = (l & 31) ^ ((j >> 2) & 3);
        ksrc[jj] = (size_t)d * LQ + (csrc << 2);
    }

    float4 acc[8];
#pragma unroll
    for (int i = 0; i < 8; ++i) acc[i] = make_float4(0.f, 0.f, 0.f, 0.f);

#pragma unroll
    for (int c = 0; c < NCH; ++c) {
        const int s0 = (p * NCH + c) << 7;  // window's 128-s base
        if (c > 0) __syncthreads();         // prior window's K reads done

        // fill K (16 glls; wave issues its 4)
#pragma unroll
        for (int jj = 0; jj < 4; ++jj)
            async_cp16(lds + (((w << 2) | jj) << 8), kb + ksrc[jj] + s0);

        // V: the thread's 16-s slice, global->reg (compiler schedules; stall
        // coverage now comes from 20-wave TLP).
        float4 vv[4][4];
        const float* vbase = vb + ((size_t)(s0 + (sp << 4)) << 5) + e0;
#pragma unroll
        for (int st = 0; st < 4; ++st)
#pragma unroll
            for (int u = 0; u < 4; ++u)
                vv[st][u] = *(const float4*)(vbase + ((st << 2) + u) * DH);

        __syncthreads();                    // K resident (drains vmcnt too)

#pragma unroll
        for (int st = 0; st < 4; ++st) {
            // K: 8 rows x b128 (4 s). chunk c = sp*4+st, read at c ^ dg.
            const int ko = (((sp << 2) + st) ^ dg) << 2;
            float4 kq[8];
#pragma unroll
            for (int i = 0; i < 8; ++i)
                kq[i] = *(const float4*)(lds + ((d0 + i) << 7) + ko);
#pragma unroll
            for (int u = 0; u < 4; ++u) {
                const float4 vu = vv[st][u];
#pragma unroll
                for (int i = 0; i < 8; ++i) {
                    const float ks = (u == 0) ? kq[i].x
                                   : (u == 1) ? kq[i].y
                                   : (u == 2) ? kq[i].z : kq[i].w;
                    fma4(acc[i], ks, vu);
                }
            }
        }
    }

    // butterfly over the wave's two sp-halves (lane ^ 32)
#pragma unroll
    for (int i = 0; i < 8; ++i) {
        acc[i].x += __shfl_xor(acc[i].x, 32);
        acc[i].y += __shfl_xor(acc[i].y, 32);
        acc[i].z += __shfl_xor(acc[i].z, 32);
        acc[i].w += __shfl_xor(acc[i].w, 32);
    }

    __syncthreads();                        // all waves' K reads done: safe to reuse lds
    if (l < 32) {                           // lane l = tile tw, wave-partial
        float* dst = lds + w * 1152 + l * 36;
#pragma unroll
        for (int i = 0; i < 8; ++i) *(float4*)(dst + (i << 2)) = acc[i];
    }
    __syncthreads();

    // final cross-wave sum; thread t owns W[d= t>>3][e4 = (t&7)*4] -> part
    const int fdg = (tid >> 6) & 3;
    const int fi  = (tid >> 3) & 7;
    const int feg = tid & 7;
    const int off = (fdg * 8 + feg) * 36 + (fi << 2);
    float4 r0 = *(const float4*)(lds + off);
    const float4 r1 = *(const float4*)(lds + 1152 + off);
    const float4 r2 = *(const float4*)(lds + 2304 + off);
    const float4 r3 = *(const float4*)(lds + 3456 + off);
    r0.x = (r0.x + r1.x) + (r2.x + r3.x);
    r0.y = (r0.y + r1.y) + (r2.y + r3.y);
    r0.z = (r0.z + r1.z) + (r2.z + r3.z);
    r0.w = (r0.w + r1.w) + (r2.w + r3.w);
    *(float4*)(part + ((size_t)p * (BS * NH) + bh) * 1024 + (tid << 2)) = r0;
}

// ---------------- Kernel B1: reduce partials over p ----------------
// 1024 blocks, one thread per (b,idx), nsp INDEPENDENT coalesced loads.
__global__ __launch_bounds__(256) void reduce_p(const float* __restrict__ part,
                                                float* __restrict__ wts, int nsp) {
    const int gidx = blockIdx.x * 256 + threadIdx.x;   // b*16384 + h*1024+d*32+e
    float s = 0.f;
#pragma unroll 8
    for (int pp = 0; pp < nsp; ++pp)
        s += part[((size_t)pp << 18) + gidx];
    wts[gidx] = s * (1.0f / 64.0f);                    // / sqrt(4096)
}

// ---------------- Kernel B2: softmax over batch axis (in-place on wts) ----------------
__global__ __launch_bounds__(256) void softmax_b(float* __restrict__ wts) {
    const int idx = blockIdx.x * 256 + threadIdx.x;    // 0..16383

    float sc[BS];
#pragma unroll
    for (int b = 0; b < BS; ++b) sc[b] = wts[((size_t)b << 14) + idx];
    float m = sc[0];
#pragma unroll
    for (int b = 1; b < BS; ++b) m = fmaxf(m, sc[b]);
    float sum = 0.f;
#pragma unroll
    for (int b = 0; b < BS; ++b) { sc[b] = __expf(sc[b] - m); sum += sc[b]; }
    const float inv = 1.0f / sum;
#pragma unroll
    for (int b = 0; b < BS; ++b) wts[((size_t)b << 14) + idx] = sc[b] * inv;
}

// ---------------- Kernel C: out = Q @ W ----------------
// 8192 blocks x 256 thr. Q tile staged in LDS (stride 36 -> conflict-free b128 reads),
// W column-block in 128 VGPRs. 1 ds_read_b128 per 16 FMA. ~26us measured.
__global__ __launch_bounds__(256, 2) void qw(const float* __restrict__ q,
                                             const float* __restrict__ wts,
                                             float* __restrict__ out) {
    __shared__ float qs[128 * 36];
    const int blk = blockIdx.x;
    const int bh  = blk >> 5;
    const int lt  = blk & 31;
    const int tid = threadIdx.x;

    const float* qbase = q + ((size_t)bh * LQ + lt * 128) * DH;

#pragma unroll
    for (int pp = 0; pp < 4; ++pp) {
        const int idx = pp * 256 + tid;           // float4 index 0..1023
        const int row = idx >> 3;
        const int c4  = idx & 7;
        const float4 t = *(const float4*)(qbase + idx * 4);
        *(float4*)(qs + row * 36 + c4 * 4) = t;
    }

    const int lsub = tid >> 3;                    // 0..31
    const int e0   = (tid & 7) << 2;

    // wts layout [b][h][d][e]: base = b*16384 + h*1024
    const int b = bh >> 4, h = bh & 15;
    float4 Wf[32];
    const float* wbase = wts + ((size_t)b << 14) + ((size_t)h << 10) + e0;
#pragma unroll
    for (int d = 0; d < 32; ++d) Wf[d] = *(const float4*)(wbase + d * DH);

    __syncthreads();

    float* obase = out + ((size_t)bh * LQ + lt * 128) * DH;

#pragma unroll
    for (int r = 0; r < 4; ++r) {
        const int lr = lsub + r * 32;
        const float* qrow = qs + lr * 36;
        float4 acc = {0, 0, 0, 0};
#pragma unroll
        for (int d4 = 0; d4 < 32; d4 += 4) {
            const float4 qv = *(const float4*)(qrow + d4);
            fma4(acc, qv.x, Wf[d4 + 0]);
            fma4(acc, qv.y, Wf[d4 + 1]);
            fma4(acc, qv.z, Wf[d4 + 2]);
            fma4(acc, qv.w, Wf[d4 + 3]);
        }
        *(float4*)(obase + (size_t)lr * DH + e0) = acc;
    }
}

extern "C" void kernel_launch(void* const* d_in, const int* in_sizes, int n_in,
                              void* d_out, int out_size, void* d_ws, size_t ws_size,
                              hipStream_t stream) {
    const float* q = (const float*)d_in[0];
    const float* k = (const float*)d_in[1];
    const float* v = (const float*)d_in[2];
    float* out  = (float*)d_out;
    float* wts  = out + OUT_ELEMS;          // attn_weights region of d_out
    float* part = (float*)d_ws;

    const size_t need32 = (size_t)32 * 256 * 1024 * 4;   // 33.55 MB of partials
    int nsp;
    if (ws_size >= need32) {
        kv_partial<1><<<256 * 32, 256, 0, stream>>>(k, v, part);
        nsp = 32;
    } else {
        kv_partial<4><<<256 * 8, 256, 0, stream>>>(k, v, part);
        nsp = 8;
    }
    reduce_p<<<(BS * HDE) / 256, 256, 0, stream>>>(part, wts, nsp);
    softmax_b<<<HDE / 256, 256, 0, stream>>>(wts);
    qw<<<BS * NH * (LQ / 128), 256, 0, stream>>>(q, wts, out);
}

// Round 16
// 138.895 us; speedup vs baseline: 1.5044x; 1.5044x over previous
//
#include <hip/hip_runtime.h>

#define BS 16
#define NH 16
#define LQ 4096
#define DH 32

constexpr size_t OUT_ELEMS = (size_t)BS * NH * LQ * DH;   // 33,554,432
constexpr int HDE = NH * DH * DH;           // 16384

// global -> LDS direct copy, 16 B per lane. dst is the WAVE-UNIFORM base;
// HW writes dst + lane*16. src is per-lane.
__device__ __forceinline__ void async_cp16(float* dst, const float* src) {
    __builtin_amdgcn_global_load_lds(
        (const __attribute__((address_space(1))) void*)src,
        (__attribute__((address_space(3))) void*)dst, 16, 0, 0);
}

__device__ __forceinline__ void fma4(float4& a, float s, const float4& v) {
    a.x = fmaf(s, v.x, a.x);
    a.y = fmaf(s, v.y, a.y);
    a.z = fmaf(s, v.z, a.z);
    a.w = fmaf(s, v.w, a.w);
}

// ---------------- Kernel A: partial K@V ----------------
// R16 design: compute phase has ZERO global loads (qw-calibration: kv's 4x gap
// vs qw = compiler-sunk mid-compute V loads). Both K and V staged via gll
// (V staging costs 0 VGPR). Thread tile 4d x 4e (acc 16) to land under the
// VGPR-64 occupancy cliff (m69: waves/CU halve at 64/128/256). 64-s window:
// K[32][64] chunk-swizzled + V[64][32] linear = 16 KB staging; reduce reuses
// it (4x64x17 = 17.4 KB total LDS -> 8-9 blocks/CU if VGPR <= 64).
// K swizzle: row r chunk c stored at slot c ^ ((r>>2)&7), applied on the gll
// SOURCE (per-instr uniform: instr j covers rows 4j..4j+4, swz = j), read at
// c ^ dg -> 8 distinct bank-quads x 8-lane broadcast = conflict-free.
// launch_bounds (256,4): VGPR cap 128 (no forced spill, R13/R15 lesson);
// occupancy comes from ACHIEVED VGPR (<=64 -> 8 blocks/CU allowed by HW).
// Wave w = s-slice [16w,16w+16) of the window; lane l = tile (dg=l>>3, eg=l&7).
template<int NCH>
__global__ __launch_bounds__(256, 4) void kv_partial(const float* __restrict__ k,
                                                     const float* __restrict__ v,
                                                     float* __restrict__ part) {
    __shared__ float lds[4608];             // staging 4096 | reduce 4352 (reused)
    const int tid = threadIdx.x;
    const int w   = tid >> 6;
    const int l   = tid & 63;
    const int nsplit = 64 / NCH;            // window = 64 s
    const int p  = blockIdx.x % nsplit;
    const int bh = blockIdx.x / nsplit;

    const int dg = l >> 3;                  // 0..7
    const int eg = l & 7;                   // 0..7
    const int d0 = dg << 2;
    const int e0 = eg << 2;

    const float* kb = k + (size_t)bh * DH * LQ;
    const float* vb = v + (size_t)bh * LQ * DH;
    float* kt = lds;                        // K[32][64], chunk-swizzled
    float* vt = lds + 2048;                 // V[64][32], linear

    // K gll: instr j (2 per wave) covers rows 4j..4j+4; lane l -> row
    // 4j + (l>>4), stored chunk cs = l&15 holds source chunk cs ^ j.
    const int j0 = w << 1, j1 = j0 + 1;
    const size_t ks0 = (size_t)((j0 << 2) + (l >> 4)) * LQ + (((l & 15) ^ j0) << 2);
    const size_t ks1 = (size_t)((j1 << 2) + (l >> 4)) * LQ + (((l & 15) ^ j1) << 2);
    const int vdst0 = (j0 << 8) + (l << 2); // V linear: instr m -> 256 floats
    const int vdst1 = (j1 << 8) + (l << 2);

    float4 acc[4];
#pragma unroll
    for (int i = 0; i < 4; ++i) acc[i] = make_float4(0.f, 0.f, 0.f, 0.f);

#pragma unroll
    for (int c = 0; c < NCH; ++c) {
        const int s0 = (p * NCH + c) << 6;  // window's 64-s base
        if (c > 0) __syncthreads();         // prior window's reads done (WAR)

        async_cp16(kt + (j0 << 8), kb + ks0 + s0);
        async_cp16(kt + (j1 << 8), kb + ks1 + s0);
        async_cp16(vt + (j0 << 8), vb + ((size_t)s0 << 5) + vdst0);
        async_cp16(vt + (j1 << 8), vb + ((size_t)s0 << 5) + vdst1);
        __syncthreads();                    // fill landed (drains vmcnt)

#pragma unroll
        for (int st = 0; st < 4; ++st) {
            const int cc = (w << 2) + st;   // chunk 0..15 (4 s each)
            const int ko = (cc ^ dg) << 2;  // swizzled slot
            float4 kq[4], vv[4];
#pragma unroll
            for (int i = 0; i < 4; ++i)
                kq[i] = *(const float4*)(kt + ((d0 + i) << 6) + ko);
#pragma unroll
            for (int u = 0; u < 4; ++u)
                vv[u] = *(const float4*)(vt + (((cc << 2) + u) << 5) + e0);
#pragma unroll
            for (int u = 0; u < 4; ++u) {
#pragma unroll
                for (int i = 0; i < 4; ++i) {
                    const float ks = (u == 0) ? kq[i].x
                                   : (u == 1) ? kq[i].y
                                   : (u == 2) ? kq[i].z : kq[i].w;
                    fma4(acc[i], ks, vv[u]);
                }
            }
        }
    }

    // reduce: 4 waves hold partials of the same 64 tiles. Stride-17 slots:
    // bank = (17*l) mod 32 is a bijection over 32 (17 odd) -> 2 lanes/bank = free.
    __syncthreads();                        // all staging reads done: reuse lds
    float* dst = lds + ((w << 6) + l) * 17;
#pragma unroll
    for (int i = 0; i < 4; ++i) *(float4*)(dst + (i << 2)) = acc[i];
    __syncthreads();

    // thread t -> W[d = t>>3][e4 = (t&7)*4]: tile tw' = (d>>2)*8 + (t&7), row q = d&3
    const int d   = tid >> 3;
    const int eg2 = tid & 7;
    const int twp = (((d >> 2)) << 3) | eg2;
    const int q   = (d & 3) << 2;
    float4 r = make_float4(0.f, 0.f, 0.f, 0.f);
#pragma unroll
    for (int ww = 0; ww < 4; ++ww) {
        const float4 t = *(const float4*)(lds + ((ww << 6) + twp) * 17 + q);
        r.x += t.x; r.y += t.y; r.z += t.z; r.w += t.w;
    }
    *(float4*)(part + ((size_t)p * (BS * NH) + bh) * 1024 + (tid << 2)) = r;
}

// ---------------- Kernel B1: reduce partials over p ----------------
// 1024 blocks, one thread per (b,idx), nsp INDEPENDENT coalesced loads.
__global__ __launch_bounds__(256) void reduce_p(const float* __restrict__ part,
                                                float* __restrict__ wts, int nsp) {
    const int gidx = blockIdx.x * 256 + threadIdx.x;   // b*16384 + h*1024+d*32+e
    float s = 0.f;
#pragma unroll 8
    for (int pp = 0; pp < nsp; ++pp)
        s += part[((size_t)pp << 18) + gidx];
    wts[gidx] = s * (1.0f / 64.0f);                    // / sqrt(4096)
}

// ---------------- Kernel B2: softmax over batch axis (in-place on wts) ----------------
__global__ __launch_bounds__(256) void softmax_b(float* __restrict__ wts) {
    const int idx = blockIdx.x * 256 + threadIdx.x;    // 0..16383

    float sc[BS];
#pragma unroll
    for (int b = 0; b < BS; ++b) sc[b] = wts[((size_t)b << 14) + idx];
    float m = sc[0];
#pragma unroll
    for (int b = 1; b < BS; ++b) m = fmaxf(m, sc[b]);
    float sum = 0.f;
#pragma unroll
    for (int b = 0; b < BS; ++b) { sc[b] = __expf(sc[b] - m); sum += sc[b]; }
    const float inv = 1.0f / sum;
#pragma unroll
    for (int b = 0; b < BS; ++b) wts[((size_t)b << 14) + idx] = sc[b] * inv;
}

// ---------------- Kernel C: out = Q @ W ----------------
// 8192 blocks x 256 thr. Q tile staged in LDS (stride 36 -> conflict-free b128 reads),
// W column-block in 128 VGPRs. 1 ds_read_b128 per 16 FMA. ~26us measured.
__global__ __launch_bounds__(256, 2) void qw(const float* __restrict__ q,
                                             const float* __restrict__ wts,
                                             float* __restrict__ out) {
    __shared__ float qs[128 * 36];
    const int blk = blockIdx.x;
    const int bh  = blk >> 5;
    const int lt  = blk & 31;
    const int tid = threadIdx.x;

    const float* qbase = q + ((size_t)bh * LQ + lt * 128) * DH;

#pragma unroll
    for (int pp = 0; pp < 4; ++pp) {
        const int idx = pp * 256 + tid;           // float4 index 0..1023
        const int row = idx >> 3;
        const int c4  = idx & 7;
        const float4 t = *(const float4*)(qbase + idx * 4);
        *(float4*)(qs + row * 36 + c4 * 4) = t;
    }

    const int lsub = tid >> 3;                    // 0..31
    const int e0   = (tid & 7) << 2;

    // wts layout [b][h][d][e]: base = b*16384 + h*1024
    const int b = bh >> 4, h = bh & 15;
    float4 Wf[32];
    const float* wbase = wts + ((size_t)b << 14) + ((size_t)h << 10) + e0;
#pragma unroll
    for (int d = 0; d < 32; ++d) Wf[d] = *(const float4*)(wbase + d * DH);

    __syncthreads();

    float* obase = out + ((size_t)bh * LQ + lt * 128) * DH;

#pragma unroll
    for (int r = 0; r < 4; ++r) {
        const int lr = lsub + r * 32;
        const float* qrow = qs + lr * 36;
        float4 acc = {0, 0, 0, 0};
#pragma unroll
        for (int d4 = 0; d4 < 32; d4 += 4) {
            const float4 qv = *(const float4*)(qrow + d4);
            fma4(acc, qv.x, Wf[d4 + 0]);
            fma4(acc, qv.y, Wf[d4 + 1]);
            fma4(acc, qv.z, Wf[d4 + 2]);
            fma4(acc, qv.w, Wf[d4 + 3]);
        }
        *(float4*)(obase + (size_t)lr * DH + e0) = acc;
    }
}

extern "C" void kernel_launch(void* const* d_in, const int* in_sizes, int n_in,
                              void* d_out, int out_size, void* d_ws, size_t ws_size,
                              hipStream_t stream) {
    const float* q = (const float*)d_in[0];
    const float* k = (const float*)d_in[1];
    const float* v = (const float*)d_in[2];
    float* out  = (float*)d_out;
    float* wts  = out + OUT_ELEMS;          // attn_weights region of d_out
    float* part = (float*)d_ws;

    const size_t need32 = (size_t)32 * 256 * 1024 * 4;   // 33.55 MB of partials
    int nsp;
    if (ws_size >= need32) {
        kv_partial<2><<<256 * 32, 256, 0, stream>>>(k, v, part);   // 2x64-s windows
        nsp = 32;
    } else {
        kv_partial<8><<<256 * 8, 256, 0, stream>>>(k, v, part);    // 8x64-s windows
        nsp = 8;
    }
    reduce_p<<<(BS * HDE) / 256, 256, 0, stream>>>(part, wts, nsp);
    softmax_b<<<HDE / 256, 256, 0, stream>>>(wts);
    qw<<<BS * NH * (LQ / 128), 256, 0, stream>>>(q, wts, out);
}

// Round 17
// 134.782 us; speedup vs baseline: 1.5503x; 1.0305x over previous
//
#include <hip/hip_runtime.h>

#define BS 16
#define NH 16
#define LQ 4096
#define DH 32

constexpr size_t OUT_ELEMS = (size_t)BS * NH * LQ * DH;   // 33,554,432
constexpr int HDE = NH * DH * DH;           // 16384

__device__ __forceinline__ void fma4(float4& a, float s, const float4& v) {
    a.x = fmaf(s, v.x, a.x);
    a.y = fmaf(s, v.y, a.y);
    a.z = fmaf(s, v.z, a.z);
    a.w = fmaf(s, v.w, a.w);
}

// ---------------- Kernel A: partial K@V — qw-clone structure ----------------
// Session calibration: qw (26us @ 2 blocks/CU) vs every kv variant (95-112us at
// ANY occupancy) isolates the winning structure: plain loads->regs->ds_write
// staging with deep per-thread MLP, ONE barrier, compute phase touching ONLY
// LDS/registers. gll's wave-level queue and compiler-sunk mid-compute V loads
// both serialize fill-latency with compute (VALUBusy ~20% at all occupancies).
// Per block: one 128-s window. Thread: 4 K float4 (row tid>>3, chunks
// {m,m+8,m+16,m+24}, per-instr 128B/row contiguous) + 4 V float4, 8 swizzled
// ds_write_b128 (write-side XOR, free with plain writes; both derived
// perfectly-packed: 8 lanes per 4-bank group), 1 barrier, 2048 FMA from LDS
// (8d x 4e tile, 48 b128 reads; read-swizzles are involutions of writes).
// K[r][c] at slot c ^ ((r>>2)&7); V[s][g] at slot g ^ (s&7).
// launch_bounds (256,2): qw-proven; no forced-VGPR spill (R13/R15 lesson).
template<int NCH>
__global__ __launch_bounds__(256, 2) void kv_partial(const float* __restrict__ k,
                                                     const float* __restrict__ v,
                                                     float* __restrict__ part) {
    __shared__ float lds[8192];             // K[32][128] swz | V[128][32] swz; reduce reuses
    const int tid = threadIdx.x;
    const int w   = tid >> 6;
    const int l   = tid & 63;
    const int nsplit = 32 / NCH;
    const int p  = blockIdx.x % nsplit;
    const int bh = blockIdx.x / nsplit;

    const int tw = tid & 31;
    const int sp = tid >> 5;                // 0..7: 16-s slice
    const int dg = tw >> 3;                 // 0..3
    const int eg = tw & 7;                  // 0..7
    const int d0 = dg << 3;                 // 8 rows
    const int e0 = eg << 2;                 // 4 cols

    const float* kb = k + (size_t)bh * DH * LQ;
    const float* vb = v + (size_t)bh * LQ * DH;
    float* kt = lds;                        // 4096 floats
    float* vt = lds + 4096;                 // 4096 floats

    // staging constants
    const int kr   = tid >> 3;              // K row 0..31
    const int km   = tid & 7;               // chunk position
    const int kswz = (kr >> 2) & 7;
    const int vs   = tid >> 1;              // V row 0..127
    const int vh   = tid & 1;               // e-half
    const int vswz = vs & 7;

    float4 acc[8];
#pragma unroll
    for (int i = 0; i < 8; ++i) acc[i] = make_float4(0.f, 0.f, 0.f, 0.f);

#pragma unroll
    for (int c = 0; c < NCH; ++c) {
        const int s0 = (p * NCH + c) << 7;  // window's 128-s base
        if (c > 0) __syncthreads();         // WAR: prior window's reads done

        // ---- stage: 8 plain float4 loads (deep MLP), then swizzled ds_writes ----
        float4 kst[4], vst[4];
#pragma unroll
        for (int j = 0; j < 4; ++j)
            kst[j] = *(const float4*)(kb + (size_t)kr * LQ + s0 + ((km + 8 * j) << 2));
#pragma unroll
        for (int j = 0; j < 4; ++j)
            vst[j] = *(const float4*)(vb + ((size_t)(s0 + vs) << 5) + (vh << 4) + (j << 2));
#pragma unroll
        for (int j = 0; j < 4; ++j)
            *(float4*)(kt + (kr << 7) + (((km + 8 * j) ^ kswz) << 2)) = kst[j];
#pragma unroll
        for (int j = 0; j < 4; ++j) {
            const int g = (vh << 2) + j;    // e-chunk 0..7
            *(float4*)(vt + (vs << 5) + ((g ^ vswz) << 2)) = vst[j];
        }
        __syncthreads();                    // tiles resident; ONE barrier per window

        // ---- compute: pure LDS + FMA (zero global ops) ----
#pragma unroll
        for (int st = 0; st < 4; ++st) {
            const int cc = (sp << 2) + st;  // s-chunk 0..31 (4 s)
            float4 kq[8];
#pragma unroll
            for (int i = 0; i < 8; ++i) {
                const int r = d0 + i;
                kq[i] = *(const float4*)(kt + (r << 7) + ((cc ^ ((r >> 2) & 7)) << 2));
            }
#pragma unroll
            for (int u = 0; u < 4; ++u) {
                const int s = (cc << 2) + u;
                const float4 vu = *(const float4*)(vt + (s << 5) + ((eg ^ (s & 7)) << 2));
#pragma unroll
                for (int i = 0; i < 8; ++i) {
                    const float ks = (u == 0) ? kq[i].x
                                   : (u == 1) ? kq[i].y
                                   : (u == 2) ? kq[i].z : kq[i].w;
                    fma4(acc[i], ks, vu);
                }
            }
        }
    }

    // ---- reduce (R12-proven, verbatim): butterfly over sp-halves, then 4 waves ----
#pragma unroll
    for (int i = 0; i < 8; ++i) {
        acc[i].x += __shfl_xor(acc[i].x, 32);
        acc[i].y += __shfl_xor(acc[i].y, 32);
        acc[i].z += __shfl_xor(acc[i].z, 32);
        acc[i].w += __shfl_xor(acc[i].w, 32);
    }

    __syncthreads();                        // all staging reads done: reuse lds
    if (l < 32) {                           // lane l = tile tw
        float* dst = lds + w * 1152 + l * 36;
#pragma unroll
        for (int i = 0; i < 8; ++i) *(float4*)(dst + (i << 2)) = acc[i];
    }
    __syncthreads();

    // final cross-wave sum; thread t owns W[d = t>>3][e4 = (t&7)*4] -> part
    const int fdg = (tid >> 6) & 3;
    const int fi  = (tid >> 3) & 7;
    const int feg = tid & 7;
    const int off = (fdg * 8 + feg) * 36 + (fi << 2);
    float4 r0 = *(const float4*)(lds + off);
    const float4 r1 = *(const float4*)(lds + 1152 + off);
    const float4 r2 = *(const float4*)(lds + 2304 + off);
    const float4 r3 = *(const float4*)(lds + 3456 + off);
    r0.x = (r0.x + r1.x) + (r2.x + r3.x);
    r0.y = (r0.y + r1.y) + (r2.y + r3.y);
    r0.z = (r0.z + r1.z) + (r2.z + r3.z);
    r0.w = (r0.w + r1.w) + (r2.w + r3.w);
    *(float4*)(part + ((size_t)p * (BS * NH) + bh) * 1024 + (tid << 2)) = r0;
}

// ---------------- Kernel B1: reduce partials over p ----------------
// 1024 blocks, one thread per (b,idx), nsp INDEPENDENT coalesced loads.
__global__ __launch_bounds__(256) void reduce_p(const float* __restrict__ part,
                                                float* __restrict__ wts, int nsp) {
    const int gidx = blockIdx.x * 256 + threadIdx.x;   // b*16384 + h*1024+d*32+e
    float s = 0.f;
#pragma unroll 8
    for (int pp = 0; pp < nsp; ++pp)
        s += part[((size_t)pp << 18) + gidx];
    wts[gidx] = s * (1.0f / 64.0f);                    // / sqrt(4096)
}

// ---------------- Kernel B2: softmax over batch axis (in-place on wts) ----------------
__global__ __launch_bounds__(256) void softmax_b(float* __restrict__ wts) {
    const int idx = blockIdx.x * 256 + threadIdx.x;    // 0..16383

    float sc[BS];
#pragma unroll
    for (int b = 0; b < BS; ++b) sc[b] = wts[((size_t)b << 14) + idx];
    float m = sc[0];
#pragma unroll
    for (int b = 1; b < BS; ++b) m = fmaxf(m, sc[b]);
    float sum = 0.f;
#pragma unroll
    for (int b = 0; b < BS; ++b) { sc[b] = __expf(sc[b] - m); sum += sc[b]; }
    const float inv = 1.0f / sum;
#pragma unroll
    for (int b = 0; b < BS; ++b) wts[((size_t)b << 14) + idx] = sc[b] * inv;
}

// ---------------- Kernel C: out = Q @ W ----------------
// 8192 blocks x 256 thr. Q tile staged in LDS (stride 36 -> conflict-free b128 reads),
// W column-block in 128 VGPRs. 1 ds_read_b128 per 16 FMA. ~26us measured.
__global__ __launch_bounds__(256, 2) void qw(const float* __restrict__ q,
                                             const float* __restrict__ wts,
                                             float* __restrict__ out) {
    __shared__ float qs[128 * 36];
    const int blk = blockIdx.x;
    const int bh  = blk >> 5;
    const int lt  = blk & 31;
    const int tid = threadIdx.x;

    const float* qbase = q + ((size_t)bh * LQ + lt * 128) * DH;

#pragma unroll
    for (int pp = 0; pp < 4; ++pp) {
        const int idx = pp * 256 + tid;           // float4 index 0..1023
        const int row = idx >> 3;
        const int c4  = idx & 7;
        const float4 t = *(const float4*)(qbase + idx * 4);
        *(float4*)(qs + row * 36 + c4 * 4) = t;
    }

    const int lsub = tid >> 3;                    // 0..31
    const int e0   = (tid & 7) << 2;

    // wts layout [b][h][d][e]: base = b*16384 + h*1024
    const int b = bh >> 4, h = bh & 15;
    float4 Wf[32];
    const float* wbase = wts + ((size_t)b << 14) + ((size_t)h << 10) + e0;
#pragma unroll
    for (int d = 0; d < 32; ++d) Wf[d] = *(const float4*)(wbase + d * DH);

    __syncthreads();

    float* obase = out + ((size_t)bh * LQ + lt * 128) * DH;

#pragma unroll
    for (int r = 0; r < 4; ++r) {
        const int lr = lsub + r * 32;
        const float* qrow = qs + lr * 36;
        float4 acc = {0, 0, 0, 0};
#pragma unroll
        for (int d4 = 0; d4 < 32; d4 += 4) {
            const float4 qv = *(const float4*)(qrow + d4);
            fma4(acc, qv.x, Wf[d4 + 0]);
            fma4(acc, qv.y, Wf[d4 + 1]);
            fma4(acc, qv.z, Wf[d4 + 2]);
            fma4(acc, qv.w, Wf[d4 + 3]);
        }
        *(float4*)(obase + (size_t)lr * DH + e0) = acc;
    }
}

extern "C" void kernel_launch(void* const* d_in, const int* in_sizes, int n_in,
                              void* d_out, int out_size, void* d_ws, size_t ws_size,
                              hipStream_t stream) {
    const float* q = (const float*)d_in[0];
    const float* k = (const float*)d_in[1];
    const float* v = (const float*)d_in[2];
    float* out  = (float*)d_out;
    float* wts  = out + OUT_ELEMS;          // attn_weights region of d_out
    float* part = (float*)d_ws;

    const size_t need32 = (size_t)32 * 256 * 1024 * 4;   // 33.55 MB of partials
    int nsp;
    if (ws_size >= need32) {
        kv_partial<1><<<256 * 32, 256, 0, stream>>>(k, v, part);
        nsp = 32;
    } else {
        kv_partial<4><<<256 * 8, 256, 0, stream>>>(k, v, part);
        nsp = 8;
    }
    reduce_p<<<(BS * HDE) / 256, 256, 0, stream>>>(part, wts, nsp);
    softmax_b<<<HDE / 256, 256, 0, stream>>>(wts);
    qw<<<BS * NH * (LQ / 128), 256, 0, stream>>>(q, wts, out);
}